// Round 11
// baseline (550.073 us; speedup 1.0000x reference)
//
#include <hip/hip_runtime.h>

typedef __attribute__((ext_vector_type(4))) float floatx4;
typedef __attribute__((ext_vector_type(8))) short bf16x8;

__device__ __forceinline__ unsigned short f2bf(float f) {
    union { float f; unsigned u; } v; v.f = f;
    unsigned r = v.u + 0x7fffu + ((v.u >> 16) & 1u);  // RNE
    return (unsigned short)(r >> 16);
}

// ---------------------------------------------------------------------------
// prep: pack weights into MFMA B-operand fragment blobs (bf16) + fuse biases.
// Wcat blob [kc=0..47][ntg=0..31][lane=0..63][j=0..7]:
//   element B[k][n], k = kc*32 + (lane>>4)*8 + j, n = ntg*16 + (lane&15)
//   k < 1024 -> W1[c][k][s] (c=n>>5, s=n&31), else W2[c][k-1024][s]
// W3 blob   [kc=0..15][ntg=0..31][lane][j]: B[k][n] = W3flat[k*512 + n]
// bias12[n] = b1flat[n] + b2flat[n];  bias3s[n] = sum_c b3[c*512+n]
// ---------------------------------------------------------------------------
__global__ void prep_kernel(const float* __restrict__ W1, const float* __restrict__ b1,
                            const float* __restrict__ W2, const float* __restrict__ b2,
                            const float* __restrict__ W3, const float* __restrict__ b3,
                            unsigned short* __restrict__ wcat, unsigned short* __restrict__ w3f,
                            float* __restrict__ bias12, float* __restrict__ bias3s)
{
    int tid = blockIdx.x * 256 + threadIdx.x;
    if (tid < 98304) {                       // 48 * 32 * 64 fragment-lanes
        int l  = tid & 63;
        int nt = (tid >> 6) & 31;
        int kc = tid >> 11;                  // 0..47
        int n  = nt * 16 + (l & 15);
        int k0 = kc * 32 + ((l >> 4) << 3);
        int c = n >> 5, s = n & 31;
        union { unsigned short us[8]; int4 v; } pk;
        const float* src = (k0 < 1024) ? (W1 + c * 32768 + k0 * 32 + s)
                                       : (W2 + c * 16384 + (k0 - 1024) * 32 + s);
        #pragma unroll
        for (int j = 0; j < 8; ++j) pk.us[j] = f2bf(src[j * 32]);
        *(int4*)(wcat + (size_t)tid * 8) = pk.v;
    } else if (tid < 131072) {               // 16 * 32 * 64 fragment-lanes for W3
        int t  = tid - 98304;
        int l  = t & 63;
        int nt = (t >> 6) & 31;
        int kc = t >> 11;                    // 0..15
        int n  = nt * 16 + (l & 15);
        int k0 = kc * 32 + ((l >> 4) << 3);
        union { unsigned short us[8]; int4 v; } pk;
        const float* src = W3 + k0 * 512 + n;
        #pragma unroll
        for (int j = 0; j < 8; ++j) pk.us[j] = f2bf(src[j * 512]);
        *(int4*)(w3f + (size_t)t * 8) = pk.v;
    } else if (tid < 131584) {
        int n = tid - 131072;
        bias12[n] = b1[n] + b2[n];
        float sacc = 0.f;
        #pragma unroll
        for (int c = 0; c < 16; ++c) sacc += b3[c * 512 + n];
        bias3s[n] = sacc;
    }
}

// ---------------------------------------------------------------------------
// fused main — DEEP-ILP / LOW-OCCUPANCY regime:
// 128 rows/block, 512 threads = 8 waves, __launch_bounds__(512,2) -> 256
// VGPR/wave. Wave w: wm = w>>2 (64-row half), wn = w&3 (128-col group);
// owns 64 rows x 128 cols: acc[4][8] = 128 VGPR.
// WHY: R3-R10 (4 schedules, 2 shapes) all pinned at 205-212 us / 28%
// MfmaUtil == the 2-barrier-structure ceiling (~670 TF). Every pipeline-
// deepening attempt at 1024 threads spilled (4 waves/SIMD forces 128-VGPR
// cap). 512-thread blocks unlock 256 VGPR: both bcur halves resident
// (64 VGPR, in-place reload after each half's last use = half-period L2
// cover), pA 16 VGPR issued mid-period for p+2, 32-MFMA clusters.
// 2 waves/SIMD: latency hidden by ILP (counted vmcnt on reg rotations),
// not TLP. Proven R10 cadence otherwise: 1 raw barrier/period (lgkm drain
// only; vmcnt survives), TOP-stage into other buffer, As XOR swizzle.
// LDS: As 2x16 KB unioned over Hf 128 KB -> 131072 B, 1 block/CU.
// Staging map: thread (sr=tid>>2, kq=tid&3) loads 16 floats (4 float4)
// k = kq*16..+15 of row sr; stages octets o = 2kq, 2kq+1 at
// [buf][half=o>>2][mtt=sr>>4][L=(o&3)*16+(sr&15)][.] with slot^=row XOR.
// MFMA 16x16x32 bf16; A-frag: lane l holds A[m=l&15][k=(l>>4)*8+j];
// B-frag: B[k=(l>>4)*8+j][n=l&15]; C/D: col=l&15, row=(l>>4)*4+reg.
// ---------------------------------------------------------------------------
__global__ __launch_bounds__(512, 2) void fused_main(
    const float* __restrict__ app, const float* __restrict__ sp,
    const unsigned short* __restrict__ wcat, const unsigned short* __restrict__ w3f,
    const float* __restrict__ bias12, const float* __restrict__ bias3s,
    float* __restrict__ out)
{
    __shared__ union {
        unsigned short As[2][2][8][64][8];   // 32 KB: [buf][half][mtt][lane][j]
        unsigned short Hf[8][16][64][8];     // 128 KB: [mtt][kc][lane][j]
    } sh;
    char* shb = (char*)&sh;

    const int tid = (int)threadIdx.x;
    const int w   = tid >> 6;                 // 0..7
    const int wm  = w >> 2;                   // 0..1 row half
    const int wn  = w & 3;                    // 0..3 col group (128 cols)
    const int l   = tid & 63;
    const int rowbase = (int)blockIdx.x * 128;

    // staging map: thread (sr, kq) holds row sr, k = p*64 + kq*16 .. +15
    const int sr = tid >> 2;                  // 0..127
    const int kq = tid & 3;                   // 0..3
    const float* appsrc = app + (size_t)(rowbase + sr) * 1024 + kq * 16;
    const float* spsrc  = sp  + (size_t)(rowbase + sr) * 512  + kq * 16;

    // swizzled write offsets for octets o0 = 2*kq, o1 = 2*kq+1
    const int mttw = sr >> 4;
    const int o0 = 2 * kq, o1 = 2 * kq + 1;
    const int L0 = (o0 & 3) * 16 + (sr & 15);
    const int L1 = (o1 & 3) * 16 + (sr & 15);
    const int wr0 = (o0 >> 2) * 8192 + mttw * 1024 + (L0 >> 3) * 128 + (((L0 & 7) ^ (L0 >> 3)) << 4);
    const int wr1 = (o1 >> 2) * 8192 + mttw * 1024 + (L1 >> 3) * 128 + (((L1 & 7) ^ (L1 >> 3)) << 4);

    // swizzled read offset (per lane, same in every region)
    const int rdoff = ((l >> 3) << 7) + (((l & 7) ^ (l >> 3)) << 4);
    #define AS_RD(buf, half, mt) \
        (*(const bf16x8*)(shb + (buf) * 16384 + (half) * 8192 + \
                          (wm * 4 + (mt)) * 1024 + rdoff))

    // stage 16 floats (4 float4) into buffer at byte base bb
    #define STAGE(bb) do {                                                    \
        union { unsigned short us[8]; int4 v; } pk;                           \
        pk.us[0] = f2bf(pA0.x); pk.us[1] = f2bf(pA0.y);                       \
        pk.us[2] = f2bf(pA0.z); pk.us[3] = f2bf(pA0.w);                       \
        pk.us[4] = f2bf(pA1.x); pk.us[5] = f2bf(pA1.y);                       \
        pk.us[6] = f2bf(pA1.z); pk.us[7] = f2bf(pA1.w);                       \
        *(int4*)(shb + (bb) + wr0) = pk.v;                                    \
        pk.us[0] = f2bf(pA2.x); pk.us[1] = f2bf(pA2.y);                       \
        pk.us[2] = f2bf(pA2.z); pk.us[3] = f2bf(pA2.w);                       \
        pk.us[4] = f2bf(pA3.x); pk.us[5] = f2bf(pA3.y);                       \
        pk.us[6] = f2bf(pA3.z); pk.us[7] = f2bf(pA3.w);                       \
        *(int4*)(shb + (bb) + wr1) = pk.v;                                    \
    } while (0)

    floatx4 acc[4][8];
    #pragma unroll
    for (int mt = 0; mt < 4; ++mt)
        #pragma unroll
        for (int nt = 0; nt < 8; ++nt)
            acc[mt][nt] = (floatx4){0.f, 0.f, 0.f, 0.f};

    // B-frag base: blob offset(kc32, ntg=wn*8+nt) = kc32*16384 + ntg*512 + l*8
    const unsigned short* wbase = wcat + (size_t)wn * 4096 + (size_t)l * 8;

    // prologue: bcur halves for period 0; stage chunk 0; load chunk 1.
    bf16x8 bc0[8], bc1[8];
    #pragma unroll
    for (int i = 0; i < 8; ++i)
        bc0[i] = *(const bf16x8*)(wbase + i * 512);
    #pragma unroll
    for (int i = 0; i < 8; ++i)
        bc1[i] = *(const bf16x8*)(wbase + 16384 + i * 512);
    float4 pA0, pA1, pA2, pA3;
    pA0 = *(const float4*)(appsrc);
    pA1 = *(const float4*)(appsrc + 4);
    pA2 = *(const float4*)(appsrc + 8);
    pA3 = *(const float4*)(appsrc + 12);
    STAGE(0);
    pA0 = *(const float4*)(appsrc + 64);      // chunk 1
    pA1 = *(const float4*)(appsrc + 68);
    pA2 = *(const float4*)(appsrc + 72);
    pA3 = *(const float4*)(appsrc + 76);
    asm volatile("s_waitcnt lgkmcnt(0)" ::: "memory");
    __builtin_amdgcn_s_barrier();

    // ---- phase 1: H_pre = [app|sp] @ Wcat, K = 1536 (24 periods of 64) ----
    for (int p = 0; p < 24; ++p) {
        const int buf = p & 1;

        // TOP: stage chunk p+1 (pA loaded mid p-1) into the other buffer
        if (p + 1 < 24)
            STAGE((buf ^ 1) * 16384);

        bf16x8 af[4];
        // half 0 (k = p*64 .. +31)
        #pragma unroll
        for (int mt = 0; mt < 4; ++mt)
            af[mt] = AS_RD(buf, 0, mt);
        __builtin_amdgcn_s_setprio(1);
        #pragma unroll
        for (int mt = 0; mt < 4; ++mt)
            #pragma unroll
            for (int nt = 0; nt < 8; ++nt)
                acc[mt][nt] = __builtin_amdgcn_mfma_f32_16x16x32_bf16(
                    af[mt], bc0[nt], acc[mt][nt], 0, 0, 0);
        __builtin_amdgcn_s_setprio(0);
        // reload bc0 for p+1 right after last use (in flight ~1 half-period)
        if (p + 1 < 24) {
            const unsigned short* wp = wbase + (size_t)(2 * (p + 1)) * 16384;
            #pragma unroll
            for (int i = 0; i < 8; ++i)
                bc0[i] = *(const bf16x8*)(wp + i * 512);
        }

        // MID: issue HBM loads for chunk p+2 (pA regs freed by top-stage)
        if (p + 2 < 24) {
            const int c = p + 2;
            const float* src = (c < 16) ? (appsrc + c * 64) : (spsrc + (c - 16) * 64);
            pA0 = *(const float4*)(src);
            pA1 = *(const float4*)(src + 4);
            pA2 = *(const float4*)(src + 8);
            pA3 = *(const float4*)(src + 12);
        }

        // half 1 (k = p*64+32 .. +63)
        #pragma unroll
        for (int mt = 0; mt < 4; ++mt)
            af[mt] = AS_RD(buf, 1, mt);
        __builtin_amdgcn_s_setprio(1);
        #pragma unroll
        for (int mt = 0; mt < 4; ++mt)
            #pragma unroll
            for (int nt = 0; nt < 8; ++nt)
                acc[mt][nt] = __builtin_amdgcn_mfma_f32_16x16x32_bf16(
                    af[mt], bc1[nt], acc[mt][nt], 0, 0, 0);
        __builtin_amdgcn_s_setprio(0);
        // reload bc1 for p+1
        if (p + 1 < 24) {
            const unsigned short* wp = wbase + (size_t)(2 * (p + 1) + 1) * 16384;
            #pragma unroll
            for (int i = 0; i < 8; ++i)
                bc1[i] = *(const bf16x8*)(wp + i * 512);
        }

        asm volatile("s_waitcnt lgkmcnt(0)" ::: "memory");
        __builtin_amdgcn_s_barrier();
    }

    // ---- phase-3 W3 prefetch (before phase-2 writes; vmcnt survives) ----
    const unsigned short* w3base = w3f + (size_t)wn * 4096 + (size_t)l * 8;
    bf16x8 b3[8];
    #pragma unroll
    for (int i = 0; i < 8; ++i)
        b3[i] = *(const bf16x8*)(w3base + i * 512);

    // ---- phase 2: relu + bias, write Hf in A-frag layout (clobbers As) ----
    #pragma unroll
    for (int nt = 0; nt < 8; ++nt) {
        const int colg = wn * 128 + nt * 16 + (l & 15);
        const float bv = bias12[colg];
        const int kc  = colg >> 5;
        const int lhi = ((colg >> 3) & 3) << 4;
        const int j   = colg & 7;
        #pragma unroll
        for (int mt = 0; mt < 4; ++mt)
            #pragma unroll
            for (int r = 0; r < 4; ++r) {
                const int rlow = ((l >> 4) << 2) + r;      // rowg & 15
                float v = acc[mt][nt][r] + bv;
                v = fmaxf(v, 0.f);
                sh.Hf[wm * 4 + mt][kc][lhi + rlow][j] = f2bf(v);
            }
    }
    asm volatile("s_waitcnt lgkmcnt(0)" ::: "memory");
    __builtin_amdgcn_s_barrier();

    // ---- phase 3: out = relu(Hf @ W3 + bias3s), K = 512, NO barriers ----
    #pragma unroll
    for (int mt = 0; mt < 4; ++mt)
        #pragma unroll
        for (int nt = 0; nt < 8; ++nt)
            acc[mt][nt] = (floatx4){0.f, 0.f, 0.f, 0.f};

    for (int kc = 0; kc < 16; ++kc) {
        bf16x8 af[4];
        #pragma unroll
        for (int mt = 0; mt < 4; ++mt)
            af[mt] = *(const bf16x8*)(&sh.Hf[wm * 4 + mt][kc][l][0]);
        __builtin_amdgcn_s_setprio(1);
        #pragma unroll
        for (int mt = 0; mt < 4; ++mt)
            #pragma unroll
            for (int nt = 0; nt < 8; ++nt)
                acc[mt][nt] = __builtin_amdgcn_mfma_f32_16x16x32_bf16(
                    af[mt], b3[nt], acc[mt][nt], 0, 0, 0);
        __builtin_amdgcn_s_setprio(0);
        if (kc + 1 < 16) {
            const unsigned short* wp = w3base + (size_t)(kc + 1) * 16384;
            #pragma unroll
            for (int i = 0; i < 8; ++i)
                b3[i] = *(const bf16x8*)(wp + i * 512);
        }
    }

    // ---- epilogue ----
    #pragma unroll
    for (int nt = 0; nt < 8; ++nt) {
        const int colg = wn * 128 + nt * 16 + (l & 15);
        const float bv = bias3s[colg];
        #pragma unroll
        for (int mt = 0; mt < 4; ++mt)
            #pragma unroll
            for (int r = 0; r < 4; ++r) {
                const int rowg = wm * 64 + mt * 16 + ((l >> 4) << 2) + r;
                float v = acc[mt][nt][r] + bv;
                v = fmaxf(v, 0.f);
                out[(size_t)(rowbase + rowg) * 512 + colg] = v;
            }
    }
    #undef AS_RD
    #undef STAGE
}

extern "C" void kernel_launch(void* const* d_in, const int* in_sizes, int n_in,
                              void* d_out, int out_size, void* d_ws, size_t ws_size,
                              hipStream_t stream)
{
    const float* app = (const float*)d_in[0];
    const float* sp  = (const float*)d_in[1];
    const float* W1  = (const float*)d_in[2];
    const float* b1  = (const float*)d_in[3];
    const float* W2  = (const float*)d_in[4];
    const float* b2  = (const float*)d_in[5];
    const float* W3  = (const float*)d_in[6];
    const float* b3  = (const float*)d_in[7];

    char* ws = (char*)d_ws;
    unsigned short* wcat  = (unsigned short*)(ws);             // 1,572,864 B
    unsigned short* w3f   = (unsigned short*)(ws + 1572864);   //   524,288 B
    float*          b12   = (float*)(ws + 2097152);            //     2,048 B
    float*          b3s   = (float*)(ws + 2099200);            //     2,048 B

    prep_kernel<<<514, 256, 0, stream>>>(W1, b1, W2, b2, W3, b3, wcat, w3f, b12, b3s);

    float* outp = (float*)d_out;
    fused_main<<<65536 / 128, 512, 0, stream>>>(app, sp, wcat, w3f, b12, b3s, outp);
}